// Round 8
// baseline (184.596 us; speedup 1.0000x reference)
//
#include <hip/hip_runtime.h>

typedef __bf16 bf16_t;
typedef __bf16 bf16x8 __attribute__((ext_vector_type(8)));
typedef __bf16 bf16x4 __attribute__((ext_vector_type(4)));
typedef float f32x4 __attribute__((ext_vector_type(4)));
typedef unsigned short u16x8 __attribute__((ext_vector_type(8)));

#define AS1C(p) ((const __attribute__((address_space(1))) void*)(p))
#define AS3(p) ((__attribute__((address_space(3))) void*)(p))
#define MM(a, b, c) __builtin_amdgcn_mfma_f32_16x16x32_bf16(a, b, c, 0, 0, 0)

__device__ __forceinline__ unsigned short f2b_rne(float f) {
  union { float f; unsigned u; } x; x.f = f;
  unsigned u = x.u;
  u += 0x7fffu + ((u >> 16) & 1u);
  return (unsigned short)(u >> 16);
}

__device__ __forceinline__ float fast_exp2(float x) {
  return __builtin_amdgcn_exp2f(x);
}

// ---------------- cast f32 -> bf16 (vectorized, 8 elts/thread) ----------------
__global__ __launch_bounds__(256) void cast_f32_bf16(const float* __restrict__ in,
                                                     unsigned short* __restrict__ out,
                                                     int n) {
  int i = (blockIdx.x * 256 + threadIdx.x) * 8;
  if (i >= n) return;
  const float4* p = reinterpret_cast<const float4*>(in + i);
  float4 a = p[0], b = p[1];
  u16x8 o;
  o[0] = f2b_rne(a.x); o[1] = f2b_rne(a.y); o[2] = f2b_rne(a.z); o[3] = f2b_rne(a.w);
  o[4] = f2b_rne(b.x); o[5] = f2b_rne(b.y); o[6] = f2b_rne(b.z); o[7] = f2b_rne(b.w);
  *reinterpret_cast<u16x8*>(out + i) = o;
}

// four 1024x1024 weight casts in one launch; out slots contiguous (2 MB apart)
__global__ __launch_bounds__(256) void cast_w4(const float* __restrict__ w0,
                                               const float* __restrict__ w1,
                                               const float* __restrict__ w2,
                                               const float* __restrict__ w3,
                                               unsigned short* __restrict__ out) {
  const float* in = (blockIdx.y == 0) ? w0 : (blockIdx.y == 1) ? w1
                  : (blockIdx.y == 2) ? w2 : w3;
  int i = (blockIdx.x * 256 + threadIdx.x) * 8;
  unsigned short* o = out + (size_t)blockIdx.y * (1024u * 1024u);
  const float4* p = reinterpret_cast<const float4*>(in + i);
  float4 a = p[0], b = p[1];
  u16x8 v;
  v[0] = f2b_rne(a.x); v[1] = f2b_rne(a.y); v[2] = f2b_rne(a.z); v[3] = f2b_rne(a.w);
  v[4] = f2b_rne(b.x); v[5] = f2b_rne(b.y); v[6] = f2b_rne(b.z); v[7] = f2b_rne(b.w);
  *reinterpret_cast<u16x8*>(o + i) = v;
}

// ============ 128x256 / BK=64 GEMM, 3-buffer counted-vmcnt pipeline ============
// C[M,N] = A[M,K] (row stride lda) * B[N,K]^T.  512 thr = 8 waves (2M x 4N); per-wave
// out 64x64 (acc[qb2][il4][jl2] = 64 VGPR).  LDS = 3 bufs x (A 128x64 + B 256x64) = 144 KiB.
// Pipeline: tile T lives in buf T%3; stage(T+2) issues during T's compute; at end of T,
// vmcnt(6) retires stage(T+1) (6 oldest of 12 outstanding) -> never drains to 0.
// XOR swizzle: LDS slot s of row r holds global col-chunk (s ^ (r&7)); inverse applied
// to the per-lane global source (global_load_lds dest must stay linear, rule #21).
// Two compute phases per tile (B-half qb=0/1); A-frags read once, reused.
template <int OUT_F32>
__global__ __launch_bounds__(512, 2) void gemm4(const bf16_t* __restrict__ A,
                                                const bf16_t* __restrict__ Bm,
                                                void* __restrict__ C,
                                                int M, int N, int K, int lda,
                                                float scale, int qlim) {
  extern __shared__ bf16_t lds[];   // 3 x 24576 elems (A 8192 + B 16384)
  const int tid = threadIdx.x;
  const int w = tid >> 6, l = tid & 63;
  const int r = l & 15, kg = l >> 4;
  const int wm64 = (w >> 2) * 64, wn32 = (w & 3) * 32;
  const int w8 = w * 8;
  const int m0 = blockIdx.y * 128, n0 = blockIdx.x * 256;
  // staging source: row = +w8 + (l>>3); col pre-swizzled (inverse XOR)
  const bf16_t* aSrc = A + (size_t)(m0 + w8 + (l >> 3)) * lda + ((l & 7) ^ (l >> 3)) * 8;
  const bf16_t* bSrc = Bm + (size_t)(n0 + w8 + (l >> 3)) * K + ((l & 7) ^ (l >> 3)) * 8;
  const int acol0 = (kg ^ (r & 7)) * 8;        // k-chunk kk=0 slot
  const int acol1 = ((4 + kg) ^ (r & 7)) * 8;  // k-chunk kk=1 slot

  f32x4 acc[2][4][2] = {};

  auto STAGE = [&](bf16_t* sb, int kt) {
    const bf16_t* ak = aSrc + kt * 64;
    const bf16_t* bk = bSrc + kt * 64;
    __builtin_amdgcn_global_load_lds(AS1C(ak),                    AS3(sb + (w8) * 64), 16, 0, 0);
    __builtin_amdgcn_global_load_lds(AS1C(ak + (size_t)64 * lda), AS3(sb + (64 + w8) * 64), 16, 0, 0);
    __builtin_amdgcn_global_load_lds(AS1C(bk),                    AS3(sb + 8192 + (w8) * 64), 16, 0, 0);
    __builtin_amdgcn_global_load_lds(AS1C(bk + (size_t)64 * K),   AS3(sb + 8192 + (64 + w8) * 64), 16, 0, 0);
    __builtin_amdgcn_global_load_lds(AS1C(bk + (size_t)128 * K),  AS3(sb + 8192 + (128 + w8) * 64), 16, 0, 0);
    __builtin_amdgcn_global_load_lds(AS1C(bk + (size_t)192 * K),  AS3(sb + 8192 + (192 + w8) * 64), 16, 0, 0);
  };

  bf16_t* cur = lds;
  bf16_t* nxt = lds + 24576;
  bf16_t* stg = lds + 49152;

  STAGE(cur, 0);
  STAGE(nxt, 1);
  asm volatile("s_waitcnt vmcnt(6)" ::: "memory");   // tile 0 landed; tile 1 in flight
  __builtin_amdgcn_s_barrier();

  const int NT = K >> 6;
  for (int t = 0; t < NT; ++t) {
    bf16x8 AF[4][2], BF[2][2][2];
#pragma unroll
    for (int il = 0; il < 4; ++il) {
      const int ao = (wm64 + il * 16 + r) * 64;
      AF[il][0] = *reinterpret_cast<const bf16x8*>(cur + ao + acol0);
      AF[il][1] = *reinterpret_cast<const bf16x8*>(cur + ao + acol1);
    }
#pragma unroll
    for (int qb = 0; qb < 2; ++qb)
#pragma unroll
      for (int jl = 0; jl < 2; ++jl) {
        const int bo = 8192 + (qb * 128 + wn32 + jl * 16 + r) * 64;
        BF[qb][jl][0] = *reinterpret_cast<const bf16x8*>(cur + bo + acol0);
        BF[qb][jl][1] = *reinterpret_cast<const bf16x8*>(cur + bo + acol1);
      }
    const int kt = (t + 2 < NT) ? t + 2 : t;   // tail: benign re-stage into unused buf
    STAGE(stg, kt);
    asm volatile("s_waitcnt lgkmcnt(4)" ::: "memory");   // A + B(qb0) resident
    __builtin_amdgcn_sched_barrier(0);
    __builtin_amdgcn_s_setprio(1);
#pragma unroll
    for (int il = 0; il < 4; ++il)
#pragma unroll
      for (int jl = 0; jl < 2; ++jl)
        acc[0][il][jl] = MM(AF[il][1], BF[0][jl][1], MM(AF[il][0], BF[0][jl][0], acc[0][il][jl]));
    __builtin_amdgcn_s_setprio(0);
    asm volatile("s_waitcnt lgkmcnt(0)" ::: "memory");   // B(qb1) resident
    __builtin_amdgcn_sched_barrier(0);
    __builtin_amdgcn_s_setprio(1);
#pragma unroll
    for (int il = 0; il < 4; ++il)
#pragma unroll
      for (int jl = 0; jl < 2; ++jl)
        acc[1][il][jl] = MM(AF[il][1], BF[1][jl][1], MM(AF[il][0], BF[1][jl][0], acc[1][il][jl]));
    __builtin_amdgcn_s_setprio(0);
    asm volatile("s_waitcnt vmcnt(6)" ::: "memory");     // next tile's 6 loads landed
    __builtin_amdgcn_s_barrier();
    bf16_t* tmp = cur; cur = nxt; nxt = stg; stg = tmp;
  }

  // epilogue: rows m0 + wm64 + il*16 + kg*4 + v; cols n0 + qb*128 + wn32 + jl*16 + r
#pragma unroll
  for (int qb = 0; qb < 2; ++qb)
#pragma unroll
    for (int il = 0; il < 4; ++il)
#pragma unroll
      for (int jl = 0; jl < 2; ++jl) {
        const int row0 = m0 + wm64 + il * 16 + kg * 4;
        const int col = n0 + qb * 128 + wn32 + jl * 16 + r;
        const float sc = (col < qlim) ? scale : 1.0f;
#pragma unroll
        for (int v = 0; v < 4; ++v) {
          float val = acc[qb][il][jl][v] * sc;
          size_t idx = (size_t)(row0 + v) * N + col;
          if (OUT_F32) reinterpret_cast<float*>(C)[idx] = val;
          else reinterpret_cast<unsigned short*>(C)[idx] = f2b_rne(val);
        }
      }
}

// ---------------- V transpose: qkv V-columns [B*S][3072](+2048) -> VT [B*H][64][2048] ----------------
__global__ __launch_bounds__(256) void transpose_v(const bf16_t* __restrict__ qkv,
                                                   bf16_t* __restrict__ vt) {
  __shared__ bf16_t Vs[64 * 72];
  const int t = threadIdx.x;
  const int s0 = blockIdx.x * 64;
  const int bh = blockIdx.y;
  const int b = bh >> 4, h = bh & 15;
  const size_t in_base = ((size_t)b * 2048 + s0) * 3072 + 2048 + h * 64;
#pragma unroll
  for (int c = 0; c < 2; ++c) {
    int chunk = c * 256 + t;
    int ss = chunk >> 3, dd = (chunk & 7) * 8;
    bf16x8 v = *reinterpret_cast<const bf16x8*>(qkv + in_base + (size_t)ss * 3072 + dd);
    *reinterpret_cast<bf16x8*>(Vs + ss * 72 + dd) = v;
  }
  __syncthreads();
  const size_t out_base = (size_t)bh * 64 * 2048 + s0;
#pragma unroll
  for (int c = 0; c < 2; ++c) {
    int chunk = c * 256 + t;
    int dd = chunk >> 3, ss = (chunk & 7) * 8;
    bf16x8 o;
#pragma unroll
    for (int j = 0; j < 8; ++j) o[j] = Vs[(ss + j) * 72 + dd];
    *reinterpret_cast<bf16x8*>(vt + out_base + (size_t)dd * 2048 + ss) = o;
  }
}

// ---------------- causal flash attention (unchanged from round 6/7) ----------------
__global__ __launch_bounds__(512) void flash_attn(const bf16_t* __restrict__ QKV,
                                                  const bf16_t* __restrict__ VT,
                                                  unsigned short* __restrict__ O,
                                                  int ostride) {
  __shared__ bf16_t Ks[2][64 * 72];
  __shared__ bf16_t Vts[2][64 * 72];
  __shared__ bf16_t Pl[8][16 * 72];
  const int tid = threadIdx.x;
  const int lane = tid & 63, wave = tid >> 6;
  const int r = lane & 15, kg = lane >> 4;
  const int bh = blockIdx.x;
  const int pair = blockIdx.y;
  const int b = bh >> 4, h = bh & 15;
  const size_t qkv_row0 = (size_t)b * 2048 * 3072;
  const int qcol = h * 64, kcol = 1024 + h * 64;
  const size_t vt_base = (size_t)bh * 64 * 2048;
  const size_t o_row0 = (size_t)b * 2048 * ostride;
  const int ocol = h * 64;
  const int srr = tid >> 3, scc = (tid & 7) * 8;

  for (int pass = 0; pass < 2; ++pass) {
    const int qt = pass ? (15 - pair) : pair;
    const int q0 = qt * 128;
    const int qrow = q0 + wave * 16 + r;
    const int tmax_w = (q0 + wave * 16 + 15) >> 6;
    const int ntiles = qt * 2 + 2;

    const size_t qoff = qkv_row0 + (size_t)qrow * 3072 + qcol;
    bf16x8 qf0 = *reinterpret_cast<const bf16x8*>(QKV + qoff + kg * 8);
    bf16x8 qf1 = *reinterpret_cast<const bf16x8*>(QKV + qoff + 32 + kg * 8);

    f32x4 oacc[4] = {};
    float m_run = -3e30f, l_lane = 0.f;

    bf16x8 gk = *reinterpret_cast<const bf16x8*>(QKV + qkv_row0 + (size_t)srr * 3072 + kcol + scc);
    bf16x8 gv = *reinterpret_cast<const bf16x8*>(VT + vt_base + (size_t)srr * 2048 + scc);

    for (int t = 0; t < ntiles; ++t) {
      const int buf = t & 1;
      *reinterpret_cast<bf16x8*>(&Ks[buf][srr * 72 + scc]) = gk;
      *reinterpret_cast<bf16x8*>(&Vts[buf][srr * 72 + scc]) = gv;
      __syncthreads();
      if (t + 1 < ntiles) {
        const int kv1 = (t + 1) * 64;
        gk = *reinterpret_cast<const bf16x8*>(QKV + qkv_row0 + (size_t)(kv1 + srr) * 3072 + kcol + scc);
        gv = *reinterpret_cast<const bf16x8*>(VT + vt_base + (size_t)srr * 2048 + kv1 + scc);
      }
      if (t > tmax_w) continue;

      const int kv0 = t * 64;
      float vals[16];
#pragma unroll
      for (int nt = 0; nt < 4; ++nt) {
        bf16x8 kf0 = *reinterpret_cast<const bf16x8*>(&Ks[buf][(nt * 16 + r) * 72 + kg * 8]);
        bf16x8 kf1 = *reinterpret_cast<const bf16x8*>(&Ks[buf][(nt * 16 + r) * 72 + 32 + kg * 8]);
        f32x4 s = {};
        __builtin_amdgcn_s_setprio(1);
        s = MM(kf0, qf0, s);
        s = MM(kf1, qf1, s);
        __builtin_amdgcn_s_setprio(0);
#pragma unroll
        for (int v = 0; v < 4; ++v) vals[nt * 4 + v] = s[v];
      }
      if (t == tmax_w) {
#pragma unroll
        for (int nt = 0; nt < 4; ++nt)
#pragma unroll
          for (int v = 0; v < 4; ++v)
            if (kv0 + nt * 16 + kg * 4 + v > qrow) vals[nt * 4 + v] = -3e30f;
      }
      float a0 = fmaxf(fmaxf(vals[0], vals[1]), vals[2]);
      float a1 = fmaxf(fmaxf(vals[3], vals[4]), vals[5]);
      float a2 = fmaxf(fmaxf(vals[6], vals[7]), vals[8]);
      float a3 = fmaxf(fmaxf(vals[9], vals[10]), vals[11]);
      float a4 = fmaxf(fmaxf(vals[12], vals[13]), vals[14]);
      float pmax = fmaxf(fmaxf(fmaxf(a0, a1), fmaxf(a2, a3)), fmaxf(a4, vals[15]));
      if (!__all(pmax <= m_run + 8.0f)) {
        pmax = fmaxf(pmax, __shfl_xor(pmax, 16));
        pmax = fmaxf(pmax, __shfl_xor(pmax, 32));
        const float m_new = fmaxf(m_run, pmax);
        const float alpha = fast_exp2(m_run - m_new);
        l_lane *= alpha;
        f32x4 al;
#pragma unroll
        for (int v = 0; v < 4; ++v) al[v] = __shfl(alpha, kg * 4 + v);
#pragma unroll
        for (int dt = 0; dt < 4; ++dt)
#pragma unroll
          for (int v = 0; v < 4; ++v) oacc[dt][v] *= al[v];
        m_run = m_new;
      }
#pragma unroll
      for (int ii = 0; ii < 16; ++ii) {
        float p = fast_exp2(vals[ii] - m_run);
        vals[ii] = p;
        l_lane += p;
      }
#pragma unroll
      for (int nt = 0; nt < 4; ++nt) {
        bf16x4 pb;
#pragma unroll
        for (int v = 0; v < 4; ++v) pb[v] = (bf16_t)vals[nt * 4 + v];
        *reinterpret_cast<bf16x4*>(&Pl[wave][r * 72 + nt * 16 + kg * 4]) = pb;
      }
      bf16x8 pa0 = *reinterpret_cast<const bf16x8*>(&Pl[wave][r * 72 + kg * 8]);
      bf16x8 pa1 = *reinterpret_cast<const bf16x8*>(&Pl[wave][r * 72 + 32 + kg * 8]);
#pragma unroll
      for (int dt = 0; dt < 4; ++dt) {
        bf16x8 vb0 = *reinterpret_cast<const bf16x8*>(&Vts[buf][(dt * 16 + r) * 72 + kg * 8]);
        bf16x8 vb1 = *reinterpret_cast<const bf16x8*>(&Vts[buf][(dt * 16 + r) * 72 + 32 + kg * 8]);
        __builtin_amdgcn_s_setprio(1);
        oacc[dt] = MM(pa0, vb0, oacc[dt]);
        oacc[dt] = MM(pa1, vb1, oacc[dt]);
        __builtin_amdgcn_s_setprio(0);
      }
    }

    float l_row = l_lane;
    l_row += __shfl_xor(l_row, 16);
    l_row += __shfl_xor(l_row, 32);
    const float linv = 1.0f / l_row;
    f32x4 il;
#pragma unroll
    for (int v = 0; v < 4; ++v) il[v] = __shfl(linv, kg * 4 + v);
    const size_t orow0 = o_row0 + (size_t)(q0 + wave * 16) * ostride + ocol;
#pragma unroll
    for (int dt = 0; dt < 4; ++dt) {
      const int d = dt * 16 + r;
#pragma unroll
      for (int v = 0; v < 4; ++v)
        O[orow0 + (size_t)(kg * 4 + v) * ostride + d] = f2b_rne(oacc[dt][v] * il[v]);
    }
  }
}

// ---------------- launcher ----------------
extern "C" void kernel_launch(void* const* d_in, const int* in_sizes, int n_in,
                              void* d_out, int out_size, void* d_ws, size_t ws_size,
                              hipStream_t stream) {
  const float* x  = (const float*)d_in[0];
  const float* Wq = (const float*)d_in[1];
  const float* Wk = (const float*)d_in[2];
  const float* Wv = (const float*)d_in[3];
  const float* Wo = (const float*)d_in[4];

  // ws layout (72 MB peak):
  //  phase 1 (casts+QKV GEMM): xb [0,16) | wqb|wkb|wvb|wob [16,24) | qkv [24,72)
  //  phase 2 (transpose/flash): vt [0,16) (xb dead); flash writes O in-place into qkv Q cols
  //  phase 3 (Wo GEMM): qkv as A (lda=3072), wob -> d_out
  char* ws = (char*)d_ws;
  bf16_t* xb  = (bf16_t*)(ws);
  bf16_t* wqb = (bf16_t*)(ws + (16u << 20));
  bf16_t* wob = (bf16_t*)(ws + (22u << 20));
  bf16_t* qkv = (bf16_t*)(ws + (24u << 20));
  bf16_t* vt  = (bf16_t*)(ws);

  // allow 144 KiB dynamic LDS for gemm4 (idempotent)
  hipFuncSetAttribute(reinterpret_cast<const void*>(&gemm4<0>),
                      hipFuncAttributeMaxDynamicSharedMemorySize, 147456);
  hipFuncSetAttribute(reinterpret_cast<const void*>(&gemm4<1>),
                      hipFuncAttributeMaxDynamicSharedMemorySize, 147456);

  const int NX = 4 * 2048 * 1024;
  cast_f32_bf16<<<NX / 2048, 256, 0, stream>>>(x, (unsigned short*)xb, NX);
  cast_w4<<<dim3(512, 4), 256, 0, stream>>>(Wq, Wk, Wv, Wo, (unsigned short*)wqb);

  // fused QKV projection: [8192,1024] x [3072,1024]^T -> [8192,3072]
  // grid (12, 64) = 768 blocks = exactly 3 rounds at 1 block/CU
  gemm4<0><<<dim3(3072 / 256, 8192 / 128), 512, 147456, stream>>>(
      xb, wqb, qkv, 8192, 3072, 1024, 1024, 0.18033688011112042f, 1024);

  transpose_v<<<dim3(2048 / 64, 64), 256, 0, stream>>>(qkv, vt);

  flash_attn<<<dim3(64, 8), 512, 0, stream>>>(qkv, vt, (unsigned short*)qkv, 3072);

  // output projection: grid (4, 64) = 256 blocks = exactly 1 round
  gemm4<1><<<dim3(1024 / 256, 8192 / 128), 512, 147456, stream>>>(
      qkv, wob, d_out, 8192, 1024, 1024, 3072, 1.0f, 0);
}